// Round 3
// baseline (3274.901 us; speedup 1.0000x reference)
//
#include <hip/hip_runtime.h>
#include <hip/hip_fp16.h>
#include <math.h>

// Problem constants
#define N_ROWS 32768
#define K_CODES 8192
#define DIM 512

// Output layout (floats): quantized_st[N,D], probs[N,K], loss, perplexity
#define OUT_Q 0
#define OUT_P ((size_t)N_ROWS * DIM)                       // 16777216
#define OUT_LOSS (OUT_P + (size_t)N_ROWS * K_CODES)        // 285212672
#define OUT_PERP (OUT_LOSS + 1)

// Workspace layout (float offsets)
#define WS_WSQ 0                        // 8192 floats
#define WS_LOSS (K_CODES)               // 8192
#define WS_CNT (K_CODES + 1)            // 8193 .. 16385
#define WS_ROWTAB 16386                 // uint64[32768] = 65536 floats (byte 65544, 8-aligned)
#define WS_F16 81928                    // f16 region base (byte 327712, 16-aligned)

// f16 region layout (in _Float16 elements, relative to f16 base)
#define XH_OFF ((size_t)0)
#define XL_OFF ((size_t)N_ROWS * DIM)
#define WH_OFF ((size_t)2 * N_ROWS * DIM)
#define WL_OFF ((size_t)2 * N_ROWS * DIM + (size_t)K_CODES * DIM)
#define F16_COUNT ((size_t)2 * (N_ROWS + K_CODES) * DIM)   // 41943040 halves
#define WS_NEEDED ((size_t)WS_F16 * 4 + F16_COUNT * 2)     // ~84.2 MB
#define WS_NEEDED_FALLBACK ((size_t)WS_F16 * 4)            // tables only

typedef _Float16 f16x8 __attribute__((ext_vector_type(8)));
typedef float f32x4 __attribute__((ext_vector_type(4)));

__device__ inline void load_lds16(const void* g, void* l) {
    __builtin_amdgcn_global_load_lds((const __attribute__((address_space(1))) void*)g,
                                     (__attribute__((address_space(3))) void*)l,
                                     16, 0, 0);
}

// Monotone float->uint key: uint order == float order (handles negatives).
__device__ inline unsigned int fkey(float f) {
    unsigned int b = __float_as_uint(f);
    return b ^ ((unsigned int)((int)b >> 31) | 0x80000000u);
}
__device__ inline float fkey_inv(unsigned int k) {
    unsigned int b = (k & 0x80000000u) ? (k ^ 0x80000000u) : ~k;
    return __uint_as_float(b);
}

// ---------------------------------------------------------------------------
// Kernel 0: row squared norms for W only (xsq is row-constant in the softmax
// and argmin -> mathematically irrelevant; dropped).
// ---------------------------------------------------------------------------
__global__ void wsq_kernel(const float* __restrict__ W, float* __restrict__ ws) {
    int row = blockIdx.x;
    int lane = threadIdx.x;  // 0..63
    const float* src = W + (size_t)row * DIM;
    float4 v0 = *(const float4*)(src + lane * 8);
    float4 v1 = *(const float4*)(src + lane * 8 + 4);
    float s = v0.x * v0.x + v0.y * v0.y + v0.z * v0.z + v0.w * v0.w
            + v1.x * v1.x + v1.y * v1.y + v1.z * v1.z + v1.w * v1.w;
#pragma unroll
    for (int off = 32; off > 0; off >>= 1) s += __shfl_down(s, off, 64);
    if (lane == 0) ws[WS_WSQ + row] = s;
}

// ---------------------------------------------------------------------------
// Kernel 0b: split X and W into fp16 hi/lo pairs (exact 3-term decomposition).
// ---------------------------------------------------------------------------
__global__ void __launch_bounds__(256) convert_split_kernel(
    const float* __restrict__ X, const float* __restrict__ W,
    _Float16* __restrict__ f16base) {
    const size_t NX8 = (size_t)N_ROWS * DIM / 8;  // 2097152
    size_t t = (size_t)blockIdx.x * 256 + threadIdx.x;
    const float* src;
    _Float16 *hd, *ld;
    if (t < NX8) {
        src = X + t * 8;
        hd = f16base + XH_OFF + t * 8;
        ld = f16base + XL_OFF + t * 8;
    } else {
        size_t u = t - NX8;
        src = W + u * 8;
        hd = f16base + WH_OFF + u * 8;
        ld = f16base + WL_OFF + u * 8;
    }
    float4 v0 = *(const float4*)src;
    float4 v1 = *(const float4*)(src + 4);
    float v[8] = {v0.x, v0.y, v0.z, v0.w, v1.x, v1.y, v1.z, v1.w};
    f16x8 h, l;
#pragma unroll
    for (int i = 0; i < 8; ++i) {
        _Float16 hv = (_Float16)v[i];
        h[i] = hv;
        l[i] = (_Float16)(v[i] - (float)hv);
    }
    *(f16x8*)hd = h;
    *(f16x8*)ld = l;
}

// ---------------------------------------------------------------------------
// Kernel 1 (MFMA): S[m,n] = wsq[n] - 2 * (x_m . w_n) via fp16 3-term split.
// Epilogue also computes per-row exact (min, argmin) into rowtab via packed
// 64-bit atomicMin (monotone key<<32 | col; smaller col wins ties).
// ---------------------------------------------------------------------------
__global__ void __launch_bounds__(256) gemm_dist_mfma_kernel(
    const _Float16* __restrict__ f16base, float* __restrict__ ws,
    float* __restrict__ out) {
    __shared__ _Float16 lds[4][128][32];  // Ah, Al, Bh, Bl : 32 KB

    const int tid = threadIdx.x;
    const int w = tid >> 6;    // wave 0..3
    const int lane = tid & 63;
    const int bn = blockIdx.x * 128;  // code tile base
    const int bm = blockIdx.y * 128;  // input-row tile base
    const int wr = w >> 1;            // wave m-quadrant (0..1)
    const int wc = w & 1;             // wave n-quadrant (0..1)

    const _Float16* src_base;
    int tile_row_base;
    if (w == 0)      { src_base = f16base + XH_OFF; tile_row_base = bm; }
    else if (w == 1) { src_base = f16base + XL_OFF; tile_row_base = bm; }
    else if (w == 2) { src_base = f16base + WH_OFF; tile_row_base = bn; }
    else             { src_base = f16base + WL_OFF; tile_row_base = bn; }

    const int lrow = lane >> 2;  // row within 16-row group
    const int p = lane & 3;      // chunk position 0..3 (8 halves each)

    f32x4 acc[4][4];
#pragma unroll
    for (int i = 0; i < 4; ++i)
#pragma unroll
        for (int j = 0; j < 4; ++j) acc[i][j] = (f32x4){0.f, 0.f, 0.f, 0.f};

    const int q = lane >> 4;    // frag k-chunk 0..3
    const int fm = lane & 15;   // frag row/col within 16

    for (int k0 = 0; k0 < DIM; k0 += 32) {
        __syncthreads();
#pragma unroll
        for (int e = 0; e < 8; ++e) {
            int m = e * 16 + lrow;
            int c = p ^ ((m >> 1) & 3);
            const _Float16* gp =
                src_base + (size_t)(tile_row_base + m) * DIM + k0 + c * 8;
            load_lds16(gp, &lds[w][e * 16][0]);
        }
        __syncthreads();

        f16x8 ah[4], al[4], bh[4], bl[4];
#pragma unroll
        for (int i = 0; i < 4; ++i) {
            int am = wr * 64 + i * 16 + fm;
            int sa = (am >> 1) & 3;
            ah[i] = *(const f16x8*)&lds[0][am][(q ^ sa) * 8];
            al[i] = *(const f16x8*)&lds[1][am][(q ^ sa) * 8];
            int bb = wc * 64 + i * 16 + fm;
            int sb = (bb >> 1) & 3;
            bh[i] = *(const f16x8*)&lds[2][bb][(q ^ sb) * 8];
            bl[i] = *(const f16x8*)&lds[3][bb][(q ^ sb) * 8];
        }
#pragma unroll
        for (int i = 0; i < 4; ++i)
#pragma unroll
            for (int j = 0; j < 4; ++j) {
                acc[i][j] = __builtin_amdgcn_mfma_f32_16x16x32_f16(
                    ah[i], bh[j], acc[i][j], 0, 0, 0);
                acc[i][j] = __builtin_amdgcn_mfma_f32_16x16x32_f16(
                    ah[i], bl[j], acc[i][j], 0, 0, 0);
                acc[i][j] = __builtin_amdgcn_mfma_f32_16x16x32_f16(
                    al[i], bh[j], acc[i][j], 0, 0, 0);
            }
    }

    // Epilogue: S = wsq[n] - 2*dot; write S; per-row packed min via shuffles
    // + one atomicMin per row per wave.
    // C/D layout: col = lane&15, row = (lane>>4)*4 + r (m89-verified)
    const float* wsq = ws + WS_WSQ;
    unsigned long long* rowtab = (unsigned long long*)(ws + WS_ROWTAB);
    float* Dout = out + OUT_P;
    const int q4 = (lane >> 4) * 4;
#pragma unroll
    for (int i = 0; i < 4; ++i) {
        unsigned long long best[4] = {~0ull, ~0ull, ~0ull, ~0ull};
#pragma unroll
        for (int j = 0; j < 4; ++j) {
            int n = bn + wc * 64 + j * 16 + fm;
            float wn = wsq[n];
#pragma unroll
            for (int r = 0; r < 4; ++r) {
                int m = bm + wr * 64 + i * 16 + q4 + r;
                float s = wn - 2.f * acc[i][j][r];
                Dout[(size_t)m * K_CODES + n] = s;
                unsigned long long pk =
                    ((unsigned long long)fkey(s) << 32) | (unsigned int)n;
                best[r] = pk < best[r] ? pk : best[r];
            }
        }
#pragma unroll
        for (int r = 0; r < 4; ++r) {
            unsigned long long b = best[r];
#pragma unroll
            for (int d = 1; d < 16; d <<= 1) {
                unsigned long long o = __shfl_xor(b, d, 64);
                b = o < b ? o : b;
            }
            if (fm == 0) {
                int m = bm + wr * 64 + i * 16 + q4 + r;
                atomicMin(rowtab + m, b);
            }
        }
    }
}

// ---------------------------------------------------------------------------
// Fallback fp32 GEMM (only if ws can't hold f16 buffers): writes S, no atomics.
// ---------------------------------------------------------------------------
#define BM 128
#define BN 128
#define BK 16

__global__ void __launch_bounds__(256) gemm_dist_fp32_kernel(
    const float* __restrict__ X, const float* __restrict__ W,
    const float* __restrict__ ws, float* __restrict__ out) {
    __shared__ float As[BK][BM];
    __shared__ float Bs[BK][BN];

    const int bn = blockIdx.x * BN;
    const int bm = blockIdx.y * BM;
    const int tid = threadIdx.x;
    const int tx = tid & 15;
    const int ty = tid >> 4;
    const int lr = tid >> 1;
    const int lc = (tid & 1) * 8;

    float acc[8][8];
#pragma unroll
    for (int i = 0; i < 8; ++i)
#pragma unroll
        for (int j = 0; j < 8; ++j) acc[i][j] = 0.f;

    const float* aptr = X + (size_t)(bm + lr) * DIM + lc;
    const float* bptr = W + (size_t)(bn + lr) * DIM + lc;

    for (int k0 = 0; k0 < DIM; k0 += BK) {
        float4 a0 = *(const float4*)(aptr + k0);
        float4 a1 = *(const float4*)(aptr + k0 + 4);
        float4 b0 = *(const float4*)(bptr + k0);
        float4 b1 = *(const float4*)(bptr + k0 + 4);
        __syncthreads();
        As[lc + 0][lr] = a0.x; As[lc + 1][lr] = a0.y;
        As[lc + 2][lr] = a0.z; As[lc + 3][lr] = a0.w;
        As[lc + 4][lr] = a1.x; As[lc + 5][lr] = a1.y;
        As[lc + 6][lr] = a1.z; As[lc + 7][lr] = a1.w;
        Bs[lc + 0][lr] = b0.x; Bs[lc + 1][lr] = b0.y;
        Bs[lc + 2][lr] = b0.z; Bs[lc + 3][lr] = b0.w;
        Bs[lc + 4][lr] = b1.x; Bs[lc + 5][lr] = b1.y;
        Bs[lc + 6][lr] = b1.z; Bs[lc + 7][lr] = b1.w;
        __syncthreads();
#pragma unroll
        for (int kk = 0; kk < BK; ++kk) {
            float a[8], b[8];
            *(float4*)&a[0] = *(const float4*)&As[kk][ty * 8];
            *(float4*)&a[4] = *(const float4*)&As[kk][ty * 8 + 4];
            *(float4*)&b[0] = *(const float4*)&Bs[kk][tx * 8];
            *(float4*)&b[4] = *(const float4*)&Bs[kk][tx * 8 + 4];
#pragma unroll
            for (int i = 0; i < 8; ++i)
#pragma unroll
                for (int j = 0; j < 8; ++j)
                    acc[i][j] = fmaf(a[i], b[j], acc[i][j]);
        }
    }

    const float* wsq = ws + WS_WSQ;
    const int m0 = bm + ty * 8;
    const int n0 = bn + tx * 8;
    float wn[8];
    *(float4*)&wn[0] = *(const float4*)(wsq + n0);
    *(float4*)&wn[4] = *(const float4*)(wsq + n0 + 4);
    float* Dout = out + OUT_P;
#pragma unroll
    for (int i = 0; i < 8; ++i) {
        float4 o0, o1;
        o0.x = wn[0] - 2.f * acc[i][0];
        o0.y = wn[1] - 2.f * acc[i][1];
        o0.z = wn[2] - 2.f * acc[i][2];
        o0.w = wn[3] - 2.f * acc[i][3];
        o1.x = wn[4] - 2.f * acc[i][4];
        o1.y = wn[5] - 2.f * acc[i][5];
        o1.z = wn[6] - 2.f * acc[i][6];
        o1.w = wn[7] - 2.f * acc[i][7];
        float* drow = Dout + (size_t)(m0 + i) * K_CODES + n0;
        *(float4*)(drow) = o0;
        *(float4*)(drow + 4) = o1;
    }
}

// Fallback rowmin scan (one block per row) -> rowtab, no atomics needed.
__global__ void __launch_bounds__(256) rowmin_scan_kernel(
    const float* __restrict__ out, float* __restrict__ ws) {
    const int n = blockIdx.x;
    const int tid = threadIdx.x;
    const float* Drow = out + OUT_P + (size_t)n * K_CODES;
    unsigned long long b = ~0ull;
    for (int j = tid; j < K_CODES; j += 256) {
        unsigned long long pk =
            ((unsigned long long)fkey(Drow[j]) << 32) | (unsigned int)j;
        b = pk < b ? pk : b;
    }
#pragma unroll
    for (int d = 1; d < 64; d <<= 1) {
        unsigned long long o = __shfl_xor(b, d, 64);
        b = o < b ? o : b;
    }
    __shared__ unsigned long long wmin[4];
    if ((tid & 63) == 0) wmin[tid >> 6] = b;
    __syncthreads();
    if (tid == 0) {
        unsigned long long m = wmin[0];
        m = wmin[1] < m ? wmin[1] : m;
        m = wmin[2] < m ? wmin[2] : m;
        m = wmin[3] < m ? wmin[3] : m;
        ((unsigned long long*)(ws + WS_ROWTAB))[n] = m;
    }
}

// ---------------------------------------------------------------------------
// Kernel 2: streaming softmax. One block per row; S row read into registers,
// e = exp(smin - s) (smin exact from rowtab), one cross-wave sum, scaled store.
// No big LDS, 1 barrier -> 8 blocks/CU, pure BW.
// ---------------------------------------------------------------------------
__global__ void __launch_bounds__(256) probs_kernel(
    float* __restrict__ out, const float* __restrict__ ws) {
    const int n = blockIdx.x;
    const int tid = threadIdx.x;
    const unsigned long long tab =
        ((const unsigned long long*)(ws + WS_ROWTAB))[n];
    const float smin = fkey_inv((unsigned int)(tab >> 32));

    float4* Drow = (float4*)(out + OUT_P + (size_t)n * K_CODES);
    float4 e[8];
    float sum = 0.f;
#pragma unroll
    for (int t = 0; t < 8; ++t) {
        float4 v = Drow[tid + t * 256];
        float4 ev;
        ev.x = __expf(smin - v.x);
        ev.y = __expf(smin - v.y);
        ev.z = __expf(smin - v.z);
        ev.w = __expf(smin - v.w);
        e[t] = ev;
        sum += ev.x + ev.y + ev.z + ev.w;
    }
#pragma unroll
    for (int off = 32; off > 0; off >>= 1) sum += __shfl_down(sum, off, 64);
    __shared__ float wsum[4];
    if ((tid & 63) == 0) wsum[tid >> 6] = sum;
    __syncthreads();
    const float inv = 1.0f / (wsum[0] + wsum[1] + wsum[2] + wsum[3]);
#pragma unroll
    for (int t = 0; t < 8; ++t) {
        float4 ev = e[t];
        ev.x *= inv; ev.y *= inv; ev.z *= inv; ev.w *= inv;
        Drow[tid + t * 256] = ev;
    }
}

// ---------------------------------------------------------------------------
// Kernel 2b: one wave per row: gather codeword, straight-through output,
// loss partial, counts histogram.
// ---------------------------------------------------------------------------
__global__ void __launch_bounds__(64) quant_loss_kernel(
    const float* __restrict__ X, const float* __restrict__ W,
    float* __restrict__ out, float* __restrict__ ws) {
    const int n = blockIdx.x;
    const int lane = threadIdx.x;
    const unsigned long long tab =
        ((const unsigned long long*)(ws + WS_ROWTAB))[n];
    const int amin = (int)(tab & 0xFFFFFFFFu);

    const float4* xr = (const float4*)(X + (size_t)n * DIM);
    const float4* wr = (const float4*)(W + (size_t)amin * DIM);
    float4* qr = (float4*)(out + OUT_Q + (size_t)n * DIM);
    float err = 0.f;
#pragma unroll
    for (int t = 0; t < 2; ++t) {
        float4 x = xr[lane + t * 64];
        float4 qv = wr[lane + t * 64];
        float4 d, o;
        d.x = qv.x - x.x; d.y = qv.y - x.y; d.z = qv.z - x.z; d.w = qv.w - x.w;
        o.x = x.x + d.x;  o.y = x.y + d.y;  o.z = x.z + d.z;  o.w = x.w + d.w;
        qr[lane + t * 64] = o;
        err += d.x * d.x + d.y * d.y + d.z * d.z + d.w * d.w;
    }
#pragma unroll
    for (int off = 32; off > 0; off >>= 1) err += __shfl_down(err, off, 64);
    if (lane == 0) {
        atomicAdd(ws + WS_LOSS, err);
        atomicAdd(ws + WS_CNT + amin, 1.0f);
    }
}

// ---------------------------------------------------------------------------
// Kernel 3: finalize loss + perplexity
// ---------------------------------------------------------------------------
__global__ void __launch_bounds__(256) finalize_kernel(
    float* __restrict__ out, const float* __restrict__ ws) {
    __shared__ float red[256];
    const int tid = threadIdx.x;
    float ent = 0.f;
    for (int j = tid; j < K_CODES; j += 256) {
        float p = ws[WS_CNT + j] * (1.0f / (float)N_ROWS);
        ent -= p * logf(p + 1e-10f);
    }
    red[tid] = ent;
    __syncthreads();
    for (int st = 128; st > 0; st >>= 1) {
        if (tid < st) red[tid] += red[tid + st];
        __syncthreads();
    }
    if (tid == 0) {
        float mse = ws[WS_LOSS] * (1.0f / ((float)N_ROWS * (float)DIM));
        out[OUT_LOSS] = mse + 0.25f * mse;
        out[OUT_PERP] = expf(red[0]);
    }
}

// ---------------------------------------------------------------------------
extern "C" void kernel_launch(void* const* d_in, const int* in_sizes, int n_in,
                              void* d_out, int out_size, void* d_ws, size_t ws_size,
                              hipStream_t stream) {
    const float* X = (const float*)d_in[0];  // [32768, 512]
    const float* W = (const float*)d_in[1];  // [8192, 512]
    float* out = (float*)d_out;
    float* ws = (float*)d_ws;

    // zero loss + counts; init rowtab to all-ones (uint64 max)
    hipMemsetAsync(ws + WS_LOSS, 0, (1 + K_CODES) * sizeof(float), stream);
    hipMemsetAsync(ws + WS_ROWTAB, 0xFF, (size_t)N_ROWS * 8, stream);

    wsq_kernel<<<K_CODES, 64, 0, stream>>>(W, ws);

    if (ws_size >= WS_NEEDED) {
        _Float16* f16base = (_Float16*)(ws + WS_F16);
        const int conv_blocks =
            (int)(((size_t)(N_ROWS + K_CODES) * DIM / 8 + 255) / 256);
        convert_split_kernel<<<conv_blocks, 256, 0, stream>>>(X, W, f16base);

        dim3 ggrid(K_CODES / 128, N_ROWS / 128);  // (64, 256)
        gemm_dist_mfma_kernel<<<ggrid, 256, 0, stream>>>(f16base, ws, out);
    } else {
        dim3 ggrid(K_CODES / BN, N_ROWS / BM);
        gemm_dist_fp32_kernel<<<ggrid, 256, 0, stream>>>(X, W, ws, out);
        rowmin_scan_kernel<<<N_ROWS, 256, 0, stream>>>(out, ws);
    }

    probs_kernel<<<N_ROWS, 256, 0, stream>>>(out, ws);
    quant_loss_kernel<<<N_ROWS, 64, 0, stream>>>(X, W, out, ws);
    finalize_kernel<<<1, 256, 0, stream>>>(out, ws);
}

// Round 4
// 2430.064 us; speedup vs baseline: 1.3477x; 1.3477x over previous
//
#include <hip/hip_runtime.h>
#include <hip/hip_fp16.h>
#include <math.h>

// Problem constants
#define N_ROWS 32768
#define K_CODES 8192
#define DIM 512

// Output layout (floats): quantized_st[N,D], probs[N,K], loss, perplexity
#define OUT_Q 0
#define OUT_P ((size_t)N_ROWS * DIM)                       // 16777216
#define OUT_LOSS (OUT_P + (size_t)N_ROWS * K_CODES)        // 285212672
#define OUT_PERP (OUT_LOSS + 1)

// Workspace layout (float offsets). NO contended accumulators: per-row error
// array reduced by finalize; histogram uses spread atomics only.
#define WS_WSQ 0                        // 8192 floats
#define WS_CNT (K_CODES)                // 8192 floats (histogram)
#define WS_ERR (2 * K_CODES)            // 32768 floats (per-row sq-err)
#define WS_F16 (2 * K_CODES + N_ROWS)   // 49152: f16 base (byte 196608, 16-aligned)

// f16 region layout (in _Float16 elements, relative to f16 base)
#define XH_OFF ((size_t)0)
#define XL_OFF ((size_t)N_ROWS * DIM)
#define WH_OFF ((size_t)2 * N_ROWS * DIM)
#define WL_OFF ((size_t)2 * N_ROWS * DIM + (size_t)K_CODES * DIM)
#define F16_COUNT ((size_t)2 * (N_ROWS + K_CODES) * DIM)   // 41943040 halves
#define WS_NEEDED ((size_t)WS_F16 * 4 + F16_COUNT * 2)     // ~84.1 MB

typedef _Float16 f16x8 __attribute__((ext_vector_type(8)));
typedef float f32x4 __attribute__((ext_vector_type(4)));

__device__ inline void load_lds16(const void* g, void* l) {
    __builtin_amdgcn_global_load_lds((const __attribute__((address_space(1))) void*)g,
                                     (__attribute__((address_space(3))) void*)l,
                                     16, 0, 0);
}

// Monotone float->uint key: uint order == float order (handles negatives).
__device__ inline unsigned int fkey(float f) {
    unsigned int b = __float_as_uint(f);
    return b ^ ((unsigned int)((int)b >> 31) | 0x80000000u);
}
__device__ inline float fkey_inv(unsigned int k) {
    unsigned int b = (k & 0x80000000u) ? (k ^ 0x80000000u) : ~k;
    return __uint_as_float(b);
}

// ---------------------------------------------------------------------------
// Kernel 0: row squared norms for W (xsq is row-constant in softmax/argmin
// -> mathematically irrelevant; dropped).
// ---------------------------------------------------------------------------
__global__ void wsq_kernel(const float* __restrict__ W, float* __restrict__ ws) {
    int row = blockIdx.x;
    int lane = threadIdx.x;  // 0..63
    const float* src = W + (size_t)row * DIM;
    float4 v0 = *(const float4*)(src + lane * 8);
    float4 v1 = *(const float4*)(src + lane * 8 + 4);
    float s = v0.x * v0.x + v0.y * v0.y + v0.z * v0.z + v0.w * v0.w
            + v1.x * v1.x + v1.y * v1.y + v1.z * v1.z + v1.w * v1.w;
#pragma unroll
    for (int off = 32; off > 0; off >>= 1) s += __shfl_down(s, off, 64);
    if (lane == 0) ws[WS_WSQ + row] = s;
}

// ---------------------------------------------------------------------------
// Kernel 0b: split X and W into fp16 hi/lo pairs (exact 3-term decomposition).
// ---------------------------------------------------------------------------
__global__ void __launch_bounds__(256) convert_split_kernel(
    const float* __restrict__ X, const float* __restrict__ W,
    _Float16* __restrict__ f16base) {
    const size_t NX8 = (size_t)N_ROWS * DIM / 8;  // 2097152
    size_t t = (size_t)blockIdx.x * 256 + threadIdx.x;
    const float* src;
    _Float16 *hd, *ld;
    if (t < NX8) {
        src = X + t * 8;
        hd = f16base + XH_OFF + t * 8;
        ld = f16base + XL_OFF + t * 8;
    } else {
        size_t u = t - NX8;
        src = W + u * 8;
        hd = f16base + WH_OFF + u * 8;
        ld = f16base + WL_OFF + u * 8;
    }
    float4 v0 = *(const float4*)src;
    float4 v1 = *(const float4*)(src + 4);
    float v[8] = {v0.x, v0.y, v0.z, v0.w, v1.x, v1.y, v1.z, v1.w};
    f16x8 h, l;
#pragma unroll
    for (int i = 0; i < 8; ++i) {
        _Float16 hv = (_Float16)v[i];
        h[i] = hv;
        l[i] = (_Float16)(v[i] - (float)hv);
    }
    *(f16x8*)hd = h;
    *(f16x8*)ld = l;
}

// ---------------------------------------------------------------------------
// Kernel 1 (MFMA): S[m,n] = wsq[n] - 2 * (x_m . w_n) via fp16 3-term split.
// Epilogue is a pure store (round-2 form): NO atomics, NO reductions.
// ---------------------------------------------------------------------------
__global__ void __launch_bounds__(256) gemm_dist_mfma_kernel(
    const _Float16* __restrict__ f16base, const float* __restrict__ ws,
    float* __restrict__ out) {
    __shared__ _Float16 lds[4][128][32];  // Ah, Al, Bh, Bl : 32 KB

    const int tid = threadIdx.x;
    const int w = tid >> 6;    // wave 0..3
    const int lane = tid & 63;
    const int bn = blockIdx.x * 128;  // code tile base
    const int bm = blockIdx.y * 128;  // input-row tile base
    const int wr = w >> 1;            // wave m-quadrant (0..1)
    const int wc = w & 1;             // wave n-quadrant (0..1)

    const _Float16* src_base;
    int tile_row_base;
    if (w == 0)      { src_base = f16base + XH_OFF; tile_row_base = bm; }
    else if (w == 1) { src_base = f16base + XL_OFF; tile_row_base = bm; }
    else if (w == 2) { src_base = f16base + WH_OFF; tile_row_base = bn; }
    else             { src_base = f16base + WL_OFF; tile_row_base = bn; }

    const int lrow = lane >> 2;  // row within 16-row group
    const int p = lane & 3;      // chunk position 0..3 (8 halves each)

    f32x4 acc[4][4];
#pragma unroll
    for (int i = 0; i < 4; ++i)
#pragma unroll
        for (int j = 0; j < 4; ++j) acc[i][j] = (f32x4){0.f, 0.f, 0.f, 0.f};

    const int q = lane >> 4;    // frag k-chunk 0..3
    const int fm = lane & 15;   // frag row/col within 16

    for (int k0 = 0; k0 < DIM; k0 += 32) {
        __syncthreads();
#pragma unroll
        for (int e = 0; e < 8; ++e) {
            int m = e * 16 + lrow;
            int c = p ^ ((m >> 1) & 3);
            const _Float16* gp =
                src_base + (size_t)(tile_row_base + m) * DIM + k0 + c * 8;
            load_lds16(gp, &lds[w][e * 16][0]);
        }
        __syncthreads();

        f16x8 ah[4], al[4], bh[4], bl[4];
#pragma unroll
        for (int i = 0; i < 4; ++i) {
            int am = wr * 64 + i * 16 + fm;
            int sa = (am >> 1) & 3;
            ah[i] = *(const f16x8*)&lds[0][am][(q ^ sa) * 8];
            al[i] = *(const f16x8*)&lds[1][am][(q ^ sa) * 8];
            int bb = wc * 64 + i * 16 + fm;
            int sb = (bb >> 1) & 3;
            bh[i] = *(const f16x8*)&lds[2][bb][(q ^ sb) * 8];
            bl[i] = *(const f16x8*)&lds[3][bb][(q ^ sb) * 8];
        }
#pragma unroll
        for (int i = 0; i < 4; ++i)
#pragma unroll
            for (int j = 0; j < 4; ++j) {
                acc[i][j] = __builtin_amdgcn_mfma_f32_16x16x32_f16(
                    ah[i], bh[j], acc[i][j], 0, 0, 0);
                acc[i][j] = __builtin_amdgcn_mfma_f32_16x16x32_f16(
                    ah[i], bl[j], acc[i][j], 0, 0, 0);
                acc[i][j] = __builtin_amdgcn_mfma_f32_16x16x32_f16(
                    al[i], bh[j], acc[i][j], 0, 0, 0);
            }
    }

    // Epilogue: S = wsq[n] - 2*dot (pure store).
    // C/D layout: col = lane&15, row = (lane>>4)*4 + r (m89-verified)
    const float* wsq = ws + WS_WSQ;
    float* Dout = out + OUT_P;
    const int q4 = (lane >> 4) * 4;
#pragma unroll
    for (int i = 0; i < 4; ++i) {
#pragma unroll
        for (int j = 0; j < 4; ++j) {
            int n = bn + wc * 64 + j * 16 + fm;
            float wn = wsq[n];
#pragma unroll
            for (int r = 0; r < 4; ++r) {
                int m = bm + wr * 64 + i * 16 + q4 + r;
                Dout[(size_t)m * K_CODES + n] = wn - 2.f * acc[i][j][r];
            }
        }
    }
}

// ---------------------------------------------------------------------------
// Fallback fp32 GEMM (only if ws can't hold f16 buffers): writes S.
// ---------------------------------------------------------------------------
#define BM 128
#define BN 128
#define BK 16

__global__ void __launch_bounds__(256) gemm_dist_fp32_kernel(
    const float* __restrict__ X, const float* __restrict__ W,
    const float* __restrict__ ws, float* __restrict__ out) {
    __shared__ float As[BK][BM];
    __shared__ float Bs[BK][BN];

    const int bn = blockIdx.x * BN;
    const int bm = blockIdx.y * BM;
    const int tid = threadIdx.x;
    const int tx = tid & 15;
    const int ty = tid >> 4;
    const int lr = tid >> 1;
    const int lc = (tid & 1) * 8;

    float acc[8][8];
#pragma unroll
    for (int i = 0; i < 8; ++i)
#pragma unroll
        for (int j = 0; j < 8; ++j) acc[i][j] = 0.f;

    const float* aptr = X + (size_t)(bm + lr) * DIM + lc;
    const float* bptr = W + (size_t)(bn + lr) * DIM + lc;

    for (int k0 = 0; k0 < DIM; k0 += BK) {
        float4 a0 = *(const float4*)(aptr + k0);
        float4 a1 = *(const float4*)(aptr + k0 + 4);
        float4 b0 = *(const float4*)(bptr + k0);
        float4 b1 = *(const float4*)(bptr + k0 + 4);
        __syncthreads();
        As[lc + 0][lr] = a0.x; As[lc + 1][lr] = a0.y;
        As[lc + 2][lr] = a0.z; As[lc + 3][lr] = a0.w;
        As[lc + 4][lr] = a1.x; As[lc + 5][lr] = a1.y;
        As[lc + 6][lr] = a1.z; As[lc + 7][lr] = a1.w;
        Bs[lc + 0][lr] = b0.x; Bs[lc + 1][lr] = b0.y;
        Bs[lc + 2][lr] = b0.z; Bs[lc + 3][lr] = b0.w;
        Bs[lc + 4][lr] = b1.x; Bs[lc + 5][lr] = b1.y;
        Bs[lc + 6][lr] = b1.z; Bs[lc + 7][lr] = b1.w;
        __syncthreads();
#pragma unroll
        for (int kk = 0; kk < BK; ++kk) {
            float a[8], b[8];
            *(float4*)&a[0] = *(const float4*)&As[kk][ty * 8];
            *(float4*)&a[4] = *(const float4*)&As[kk][ty * 8 + 4];
            *(float4*)&b[0] = *(const float4*)&Bs[kk][tx * 8];
            *(float4*)&b[4] = *(const float4*)&Bs[kk][tx * 8 + 4];
#pragma unroll
            for (int i = 0; i < 8; ++i)
#pragma unroll
                for (int j = 0; j < 8; ++j)
                    acc[i][j] = fmaf(a[i], b[j], acc[i][j]);
        }
    }

    const float* wsq = ws + WS_WSQ;
    const int m0 = bm + ty * 8;
    const int n0 = bn + tx * 8;
    float wn[8];
    *(float4*)&wn[0] = *(const float4*)(wsq + n0);
    *(float4*)&wn[4] = *(const float4*)(wsq + n0 + 4);
    float* Dout = out + OUT_P;
#pragma unroll
    for (int i = 0; i < 8; ++i) {
        float4 o0, o1;
        o0.x = wn[0] - 2.f * acc[i][0];
        o0.y = wn[1] - 2.f * acc[i][1];
        o0.z = wn[2] - 2.f * acc[i][2];
        o0.w = wn[3] - 2.f * acc[i][3];
        o1.x = wn[4] - 2.f * acc[i][4];
        o1.y = wn[5] - 2.f * acc[i][5];
        o1.z = wn[6] - 2.f * acc[i][6];
        o1.w = wn[7] - 2.f * acc[i][7];
        float* drow = Dout + (size_t)(m0 + i) * K_CODES + n0;
        *(float4*)(drow) = o0;
        *(float4*)(drow + 4) = o1;
    }
}

// ---------------------------------------------------------------------------
// Kernel 2 (fused): one block per row. Register-stage the S row; packed
// (min,argmin) from registers; softmax in place; gather W[amin]; write
// quantized_st; per-row sq-err to ws (NON-atomic); spread histogram atomic.
// ---------------------------------------------------------------------------
__global__ void __launch_bounds__(256) probs_quant_kernel(
    const float* __restrict__ X, const float* __restrict__ W,
    float* __restrict__ out, float* __restrict__ ws) {
    const int n = blockIdx.x;
    const int tid = threadIdx.x;
    __shared__ unsigned long long mred[4];
    __shared__ float fred[4];

    float4* Drow4 = (float4*)(out + OUT_P + (size_t)n * K_CODES);

    // Load row into registers; packed min (key<<32 | col) on the fly.
    float4 e[8];
    unsigned long long best = ~0ull;
#pragma unroll
    for (int t = 0; t < 8; ++t) {
        float4 v = Drow4[tid + t * 256];
        e[t] = v;
        unsigned int c0 = (unsigned int)((tid + t * 256) * 4);
        unsigned long long k;
        k = ((unsigned long long)fkey(v.x) << 32) | (c0 + 0u);
        best = k < best ? k : best;
        k = ((unsigned long long)fkey(v.y) << 32) | (c0 + 1u);
        best = k < best ? k : best;
        k = ((unsigned long long)fkey(v.z) << 32) | (c0 + 2u);
        best = k < best ? k : best;
        k = ((unsigned long long)fkey(v.w) << 32) | (c0 + 3u);
        best = k < best ? k : best;
    }
#pragma unroll
    for (int d = 1; d < 64; d <<= 1) {
        unsigned long long o = __shfl_xor(best, d, 64);
        best = o < best ? o : best;
    }
    if ((tid & 63) == 0) mred[tid >> 6] = best;
    __syncthreads();
    unsigned long long bm = mred[0];
    bm = mred[1] < bm ? mred[1] : bm;
    bm = mred[2] < bm ? mred[2] : bm;
    bm = mred[3] < bm ? mred[3] : bm;
    const float smin = fkey_inv((unsigned int)(bm >> 32));
    const int amin = (int)(bm & 0xFFFFFFFFu);

    // exp(smin - s) in registers; block sum.
    float sum = 0.f;
#pragma unroll
    for (int t = 0; t < 8; ++t) {
        float4 v = e[t];
        float4 ev;
        ev.x = __expf(smin - v.x);
        ev.y = __expf(smin - v.y);
        ev.z = __expf(smin - v.z);
        ev.w = __expf(smin - v.w);
        e[t] = ev;
        sum += ev.x + ev.y + ev.z + ev.w;
    }
#pragma unroll
    for (int off = 32; off > 0; off >>= 1) sum += __shfl_down(sum, off, 64);
    if ((tid & 63) == 0) fred[tid >> 6] = sum;
    __syncthreads();
    const float inv = 1.0f / (fred[0] + fred[1] + fred[2] + fred[3]);

    // normalized store (in place)
#pragma unroll
    for (int t = 0; t < 8; ++t) {
        float4 ev = e[t];
        ev.x *= inv; ev.y *= inv; ev.z *= inv; ev.w *= inv;
        Drow4[tid + t * 256] = ev;
    }

    // quantize + straight-through + per-row error (2 floats per thread)
    const float2* xr = (const float2*)(X + (size_t)n * DIM);
    const float2* wr = (const float2*)(W + (size_t)amin * DIM);
    float2* qr = (float2*)(out + OUT_Q + (size_t)n * DIM);
    float2 x = xr[tid];
    float2 qv = wr[tid];
    float2 d2, o;
    d2.x = qv.x - x.x; d2.y = qv.y - x.y;
    o.x = x.x + d2.x;  o.y = x.y + d2.y;
    qr[tid] = o;
    float err = d2.x * d2.x + d2.y * d2.y;
#pragma unroll
    for (int off = 32; off > 0; off >>= 1) err += __shfl_down(err, off, 64);
    __syncthreads();  // WAR: everyone done reading fred before overwrite
    if ((tid & 63) == 0) fred[tid >> 6] = err;
    __syncthreads();
    if (tid == 0) {
        ws[WS_ERR + n] = fred[0] + fred[1] + fred[2] + fred[3];
        atomicAdd(ws + WS_CNT + amin, 1.0f);  // spread over 8192 addrs
    }
}

// ---------------------------------------------------------------------------
// Kernel 3: finalize loss (reduce per-row errors) + perplexity (counts).
// ---------------------------------------------------------------------------
__global__ void __launch_bounds__(256) finalize_kernel(
    float* __restrict__ out, const float* __restrict__ ws) {
    __shared__ float red[256];
    const int tid = threadIdx.x;

    float errsum = 0.f;
    for (int j = tid; j < N_ROWS; j += 256) errsum += ws[WS_ERR + j];
    red[tid] = errsum;
    __syncthreads();
    for (int st = 128; st > 0; st >>= 1) {
        if (tid < st) red[tid] += red[tid + st];
        __syncthreads();
    }
    const float total_err = red[0];
    __syncthreads();

    float ent = 0.f;
    for (int j = tid; j < K_CODES; j += 256) {
        float p = ws[WS_CNT + j] * (1.0f / (float)N_ROWS);
        ent -= p * logf(p + 1e-10f);
    }
    red[tid] = ent;
    __syncthreads();
    for (int st = 128; st > 0; st >>= 1) {
        if (tid < st) red[tid] += red[tid + st];
        __syncthreads();
    }
    if (tid == 0) {
        float mse = total_err * (1.0f / ((float)N_ROWS * (float)DIM));
        out[OUT_LOSS] = mse + 0.25f * mse;
        out[OUT_PERP] = expf(red[0]);
    }
}

// ---------------------------------------------------------------------------
extern "C" void kernel_launch(void* const* d_in, const int* in_sizes, int n_in,
                              void* d_out, int out_size, void* d_ws, size_t ws_size,
                              hipStream_t stream) {
    const float* X = (const float*)d_in[0];  // [32768, 512]
    const float* W = (const float*)d_in[1];  // [8192, 512]
    float* out = (float*)d_out;
    float* ws = (float*)d_ws;

    // zero the histogram (ws is poisoned 0xAA); WS_ERR is fully overwritten
    hipMemsetAsync(ws + WS_CNT, 0, K_CODES * sizeof(float), stream);

    wsq_kernel<<<K_CODES, 64, 0, stream>>>(W, ws);

    if (ws_size >= WS_NEEDED) {
        _Float16* f16base = (_Float16*)(ws + WS_F16);
        const int conv_blocks =
            (int)(((size_t)(N_ROWS + K_CODES) * DIM / 8 + 255) / 256);
        convert_split_kernel<<<conv_blocks, 256, 0, stream>>>(X, W, f16base);

        dim3 ggrid(K_CODES / 128, N_ROWS / 128);  // (64, 256)
        gemm_dist_mfma_kernel<<<ggrid, 256, 0, stream>>>(f16base, ws, out);
    } else {
        dim3 ggrid(K_CODES / BN, N_ROWS / BM);
        gemm_dist_fp32_kernel<<<ggrid, 256, 0, stream>>>(X, W, ws, out);
    }

    probs_quant_kernel<<<N_ROWS, 256, 0, stream>>>(X, W, out, ws);
    finalize_kernel<<<1, 256, 0, stream>>>(out, ws);
}